// Round 3
// baseline (1171.872 us; speedup 1.0000x reference)
//
#include <hip/hip_runtime.h>
#include <hip/hip_bf16.h>

using bf16 = __hip_bfloat16;
typedef __attribute__((ext_vector_type(8))) short short8;
typedef __attribute__((ext_vector_type(4))) float f32x4;

static __device__ __forceinline__ float bf2f(bf16 v) { return __bfloat162float(v); }
static __device__ __forceinline__ bf16 f2bf(float v) { return __float2bfloat16(v); }

// ---- problem constants ----
constexpr int CB = 4, CT = 1024, CC = 1024, CH = 16, CHD = 64, CLAT = 512;
constexpr int CE = 8, CF = 1024, CNS = 2;
constexpr int NTOK = CB * CT;            // 4096
constexpr int FUP = CE * CF + CNS * CF;  // 10240

struct alignas(8) bf16x4 { bf16 a, b, c, d; };

// =====================================================================
// Weight pack: dst[n][k](+z) = bf16(src[k][n](+z)); optional lo plane.
// =====================================================================
__global__ void pack_t_kernel(const float* __restrict__ src, bf16* __restrict__ dst,
                              int K, int N, int lddst, long srcZ, long dstZ, long plane) {
  __shared__ float tile[32][33];
  src += (long)blockIdx.z * srcZ;
  dst += (long)blockIdx.z * dstZ;
  int k0 = blockIdx.y * 32, n0 = blockIdx.x * 32;
  int tx = threadIdx.x, ty = threadIdx.y;  // 32 x 8
#pragma unroll
  for (int i = 0; i < 32; i += 8) {
    int k = k0 + ty + i, n = n0 + tx;
    tile[ty + i][tx] = (k < K && n < N) ? src[(long)k * N + n] : 0.f;
  }
  __syncthreads();
#pragma unroll
  for (int i = 0; i < 32; i += 8) {
    int n = n0 + ty + i, k = k0 + tx;
    if (n < N && k < K) {
      float v = tile[tx][ty + i];
      bf16 hi = f2bf(v);
      long idx = (long)n * lddst + k;
      dst[idx] = hi;
      if (plane) dst[idx + plane] = f2bf(v - bf2f(hi));
    }
  }
}

// =====================================================================
// RMSNorm: row of C=1024 fp32 -> bf16 (optionally split hi/lo).
// =====================================================================
template<bool SPLIT>
__global__ void rmsnorm_kernel(const float* __restrict__ x, const float* __restrict__ g,
                               bf16* __restrict__ ob, long plane) {
  int row = blockIdx.x;
  int t = threadIdx.x;  // 256
  const float4* xr = (const float4*)(x + (long)row * CC);
  float4 v = xr[t];
  float ss = v.x * v.x + v.y * v.y + v.z * v.z + v.w * v.w;
#pragma unroll
  for (int o = 32; o > 0; o >>= 1) ss += __shfl_down(ss, o);
  __shared__ float wsum[4];
  if ((t & 63) == 0) wsum[t >> 6] = ss;
  __syncthreads();
  float tot = wsum[0] + wsum[1] + wsum[2] + wsum[3];
  float r = rsqrtf(tot * (1.f / CC) + 1e-6f);
  const float4* gr = (const float4*)g;
  float4 gv = gr[t];
  float o0 = v.x * r * gv.x, o1 = v.y * r * gv.y, o2 = v.z * r * gv.z, o3 = v.w * r * gv.w;
  long base = (long)row * CC + t * 4;
  bf16x4 hv = {f2bf(o0), f2bf(o1), f2bf(o2), f2bf(o3)};
  *(bf16x4*)(ob + base) = hv;
  if (SPLIT) {
    bf16x4 lv = {f2bf(o0 - bf2f(hv.a)), f2bf(o1 - bf2f(hv.b)),
                 f2bf(o2 - bf2f(hv.c)), f2bf(o3 - bf2f(hv.d))};
    *(bf16x4*)(ob + plane + base) = lv;
  }
}

// =====================================================================
// Router (fused rmsnorm): one wave per token. fp32 logits, top-2
// (lowest-index tie-break like jax.lax.top_k), softmax over the
// selected ORIGINAL logits -> wf[n][E].
// =====================================================================
__global__ void router_kernel(const float* __restrict__ hb, const float* __restrict__ g,
                              const float* __restrict__ wr, const float* __restrict__ rb,
                              float* __restrict__ wf) {
  int n = blockIdx.x, l = threadIdx.x;  // 64
  const float* hrow = hb + (long)n * CC;
  float xs[16];
  float ss = 0.f;
#pragma unroll
  for (int i = 0; i < 16; i++) {
    float xv = hrow[i * 64 + l];
    xs[i] = xv;
    ss += xv * xv;
  }
#pragma unroll
  for (int o = 32; o > 0; o >>= 1) ss += __shfl_xor(ss, o);
  float r = rsqrtf(ss * (1.f / CC) + 1e-6f);
  float acc[CE];
#pragma unroll
  for (int e = 0; e < CE; e++) acc[e] = 0.f;
#pragma unroll
  for (int i = 0; i < 16; i++) {
    int c = i * 64 + l;
    float v = xs[i] * r * g[c];
    const float* w = wr + (long)c * CE;
#pragma unroll
    for (int e = 0; e < CE; e++) acc[e] += v * w[e];
  }
#pragma unroll
  for (int e = 0; e < CE; e++)
#pragma unroll
    for (int o = 32; o > 0; o >>= 1) acc[e] += __shfl_down(acc[e], o);
  if (l == 0) {
    float lg[CE], bi[CE];
#pragma unroll
    for (int e = 0; e < CE; e++) { lg[e] = acc[e] * (1.f / 32.f); bi[e] = lg[e] + rb[e]; }
    int i1 = 0;
#pragma unroll
    for (int e = 1; e < CE; e++) if (bi[e] > bi[i1]) i1 = e;
    int i2 = -1;
#pragma unroll
    for (int e = 0; e < CE; e++) if (e != i1 && (i2 < 0 || bi[e] > bi[i2])) i2 = e;
    float mx = fmaxf(lg[i1], lg[i2]);
    float e1 = expf(lg[i1] - mx), e2 = expf(lg[i2] - mx);
    float inv = 1.f / (e1 + e2);
#pragma unroll
    for (int e = 0; e < CE; e++) wf[(long)n * CE + e] = 0.f;
    wf[(long)n * CE + i1] = e1 * inv;
    wf[(long)n * CE + i2] = e2 * inv;
  }
}

// =====================================================================
// Causal softmax, IN PLACE over split-bf16 scores slab [16][1024][1024].
// Applies 1/sqrt(64). One row per wave; reads i<len, writes all 1024
// (zeros past the diagonal). Block 256 = 4 waves.
// =====================================================================
__global__ void softmax_kernel(bf16* __restrict__ scp, long plane) {
  int wid = threadIdx.x >> 6, l = threadIdx.x & 63;
  long rowid = (long)blockIdx.x * 4 + wid;  // h*1024 + t
  int t = (int)(rowid & (CT - 1));
  bf16* row = scp + rowid * CT;
  int len = t + 1;
  float v[16];
  float m = -1e30f;
#pragma unroll
  for (int ii = 0; ii < 16; ii++) {
    int i = ii * 64 + l;
    v[ii] = (i < len) ? (bf2f(row[i]) + bf2f(row[i + plane])) * 0.125f : -1e30f;
    m = fmaxf(m, v[ii]);
  }
#pragma unroll
  for (int o = 32; o > 0; o >>= 1) m = fmaxf(m, __shfl_xor(m, o));
  float s = 0.f;
#pragma unroll
  for (int ii = 0; ii < 16; ii++) { v[ii] = expf(v[ii] - m); s += v[ii]; }
#pragma unroll
  for (int o = 32; o > 0; o >>= 1) s += __shfl_xor(s, o);
  float inv = 1.f / s;
#pragma unroll
  for (int ii = 0; ii < 16; ii++) {
    int i = ii * 64 + l;
    float pv = v[ii] * inv;
    bf16 hi = f2bf(pv);
    row[i] = hi;
    row[i + plane] = f2bf(pv - bf2f(hi));
  }
}

// =====================================================================
// Generic MFMA GEMM, Bt ([N,K]) operand layout, 128xBN tile, BK=32,
// 4 waves, global_load_lds(16B) staging (m97 structure).
// MODE: 0 = plain bf16, 1 = split hi/lo (3 MFMA terms), 2 = dual-B (SwiGLU).
// EPI:  1 split-bf16 store | 2 f32 resid add | 3 k/v split | 4 SwiGLU*w
// z offsets: off = (z/zdiv)*s?z1 + (z%zdiv)*s?z2
// =====================================================================
constexpr int EPI_SPLIT = 1, EPI_ADD = 2, EPI_KV = 3, EPI_SWIGLU = 4;

template<int BN, int EPI, int MODE>
__global__ __launch_bounds__(256) void gemm_bt(
    const bf16* __restrict__ A, long lda, long planeA,
    const bf16* __restrict__ B1, const bf16* __restrict__ B3, long ldb,
    void* __restrict__ Cv, long ldc, long planeC,
    int M, int N, int K,
    int zdiv, long sAz1, long sAz2, long sBz1, long sBz2, long sCz1, long sCz2,
    const float* __restrict__ aux1, void* __restrict__ aux2, int causal) {
  constexpr int BM = 128, BK = 32;
  constexpr int PA = (MODE == 1) ? 2 : 1;
  constexpr int PB = (MODE == 0) ? 1 : 2;
  constexpr int WN = (BN == 128) ? 2 : 1;
  constexpr int WM = 4 / WN;
  constexpr int FM = BM / (16 * WM);
  constexpr int FN = BN / (16 * WN);
  constexpr int ITA = (BM * BK / 8) / 256;
  constexpr int ITB = (BN * BK / 8) / 256;
  constexpr int A3 = (MODE == 2) ? FM : 1;
  constexpr int B3N = (MODE == 2) ? FN : 1;

  __shared__ bf16 As[PA][BM][BK];
  __shared__ bf16 Bs[PB][BN][BK];

  int z = blockIdx.z;
  int z1 = z / zdiv, z2 = z % zdiv;
  long offA = (long)z1 * sAz1 + (long)z2 * sAz2;
  long offB = (long)z1 * sBz1 + (long)z2 * sBz2;
  long offC = (long)z1 * sCz1 + (long)z2 * sCz2;

  int m0 = blockIdx.y * BM;
  int n0 = blockIdx.x * BN;
  if (causal && n0 > m0 + (BM - 1)) return;  // block fully above diagonal

  int tid = threadIdx.x;
  int wid = tid >> 6, lane = tid & 63;
  int wrow = (wid / WN) * (BM / WM);
  int wcol = (wid % WN) * (BN / WN);
  int lr = lane & 15, lk8 = (lane >> 4) * 8;

  const bf16* Ap0 = A + offA;
  const bf16* Ap1 = Ap0 + planeA;
  const bf16* Bp0 = B1 + offB;
  const bf16* Bp1 = B3 + offB;

  f32x4 acc[FM][FN] = {};
  f32x4 acc3[A3][B3N] = {};

  for (int k0 = 0; k0 < K; k0 += BK) {
    __syncthreads();
#pragma unroll
    for (int p = 0; p < PA; p++) {
      const bf16* Ap = p ? Ap1 : Ap0;
#pragma unroll
      for (int i = 0; i < ITA; i++) {
        int c = i * 256 + wid * 64 + lane;
        int r = c >> 2;
        int kc = (c & 3) * 8;
        __builtin_amdgcn_global_load_lds(
            (const __attribute__((address_space(1))) void*)(const void*)(Ap + (long)(m0 + r) * lda + (k0 + kc)),
            (__attribute__((address_space(3))) void*)(void*)(&As[p][0][0] + (i * 256 + wid * 64) * 8),
            16, 0, 0);
      }
    }
#pragma unroll
    for (int p = 0; p < PB; p++) {
      const bf16* Bp = p ? Bp1 : Bp0;
#pragma unroll
      for (int i = 0; i < ITB; i++) {
        int c = i * 256 + wid * 64 + lane;
        int r = c >> 2;
        int kc = (c & 3) * 8;
        __builtin_amdgcn_global_load_lds(
            (const __attribute__((address_space(1))) void*)(const void*)(Bp + (long)(n0 + r) * ldb + (k0 + kc)),
            (__attribute__((address_space(3))) void*)(void*)(&Bs[p][0][0] + (i * 256 + wid * 64) * 8),
            16, 0, 0);
      }
    }
    __syncthreads();

    short8 av[PA][FM], bv[PB][FN];
#pragma unroll
    for (int p = 0; p < PA; p++)
#pragma unroll
      for (int m = 0; m < FM; m++)
        av[p][m] = *(const short8*)&As[p][wrow + m * 16 + lr][lk8];
#pragma unroll
    for (int p = 0; p < PB; p++)
#pragma unroll
      for (int n = 0; n < FN; n++)
        bv[p][n] = *(const short8*)&Bs[p][wcol + n * 16 + lr][lk8];

#pragma unroll
    for (int m = 0; m < FM; m++)
#pragma unroll
      for (int n = 0; n < FN; n++) {
        if constexpr (MODE == 0) {
          acc[m][n] = __builtin_amdgcn_mfma_f32_16x16x32_bf16(av[0][m], bv[0][n], acc[m][n], 0, 0, 0);
        } else if constexpr (MODE == 1) {
          acc[m][n] = __builtin_amdgcn_mfma_f32_16x16x32_bf16(av[0][m], bv[0][n], acc[m][n], 0, 0, 0);
          acc[m][n] = __builtin_amdgcn_mfma_f32_16x16x32_bf16(av[0][m], bv[1][n], acc[m][n], 0, 0, 0);
          acc[m][n] = __builtin_amdgcn_mfma_f32_16x16x32_bf16(av[1][m], bv[0][n], acc[m][n], 0, 0, 0);
        } else {
          acc[m][n]  = __builtin_amdgcn_mfma_f32_16x16x32_bf16(av[0][m], bv[0][n], acc[m][n], 0, 0, 0);
          acc3[m][n] = __builtin_amdgcn_mfma_f32_16x16x32_bf16(av[0][m], bv[1][n], acc3[m][n], 0, 0, 0);
        }
      }
  }

  // ---- epilogue: C/D layout col=lane&15, row=(lane>>4)*4+reg ----
#pragma unroll
  for (int m = 0; m < FM; m++)
#pragma unroll
    for (int n = 0; n < FN; n++) {
      int col = n0 + wcol + n * 16 + lr;
      if (col < N) {
#pragma unroll
        for (int r = 0; r < 4; r++) {
          int row = m0 + wrow + m * 16 + (lane >> 4) * 4 + r;
          float val = acc[m][n][r];
          if constexpr (EPI == EPI_SPLIT) {
            bf16 hi = f2bf(val);
            long ci = offC + (long)row * ldc + col;
            ((bf16*)Cv)[ci] = hi;
            ((bf16*)Cv)[ci + planeC] = f2bf(val - bf2f(hi));
          } else if constexpr (EPI == EPI_ADD) {
            long ci = (long)row * ldc + col;
            ((float*)Cv)[ci] = aux1[ci] + val;
          } else if constexpr (EPI == EPI_KV) {
            bf16 hi = f2bf(val);
            bf16 lo = f2bf(val - bf2f(hi));
            if (col < CHD) {  // k: [tok][64]
              long ci = (long)row * CHD + col;
              ((bf16*)Cv)[ci] = hi;
              ((bf16*)Cv)[ci + 262144] = lo;
            } else {          // v transposed: [b][d][t]
              int d = col - CHD;
              long vi = ((long)(row >> 10) * CHD + d) * CT + (row & (CT - 1));
              ((bf16*)aux2)[vi] = hi;
              ((bf16*)aux2)[vi + 262144] = lo;
            }
          } else if constexpr (EPI == EPI_SWIGLU) {
            float g3 = (MODE == 2) ? acc3[m][n][r] : 0.f;
            float sl = g3 / (1.f + expf(-g3));
            float wt = (col < CE * CF) ? aux1[(long)row * CE + (col >> 10)] : 1.f;
            ((bf16*)Cv)[(long)row * ldc + col] = f2bf(val * sl * wt);
          }
        }
      }
    }
}

// =====================================================================
// Launcher — manual workspace arena with lifetime-based aliasing.
// Peak use ~193 MB.
// =====================================================================
extern "C" void kernel_launch(void* const* d_in, const int* in_sizes, int n_in,
                              void* d_out, int out_size, void* d_ws, size_t ws_size,
                              hipStream_t stream) {
  (void)in_sizes; (void)n_in; (void)out_size; (void)ws_size;
  const float* x        = (const float*)d_in[0];
  const float* g_attn   = (const float*)d_in[1];
  const float* wq       = (const float*)d_in[2];
  const float* wkv_down = (const float*)d_in[3];
  const float* wk_up    = (const float*)d_in[4];
  const float* wv_up    = (const float*)d_in[5];
  const float* wo       = (const float*)d_in[6];
  const float* g_moe    = (const float*)d_in[7];
  const float* wr       = (const float*)d_in[8];
  const float* rb       = (const float*)d_in[9];
  const float* e_w1     = (const float*)d_in[10];
  const float* e_w2     = (const float*)d_in[11];
  const float* e_w3     = (const float*)d_in[12];
  const float* s_w1     = (const float*)d_in[13];
  const float* s_w2     = (const float*)d_in[14];
  const float* s_w3     = (const float*)d_in[15];
  float* out = (float*)d_out;

  char* base = (char*)d_ws;
  // ---- persistent (byte offsets, all 256-aligned) ----
  bf16*  WqT    = (bf16*)(base + 0);           // [2][1024][1024], lo at +1048576 el
  bf16*  WkvT   = (bf16*)(base + 4194304);     // [2][512][1024],  lo at +524288
  bf16*  WkvupT = (bf16*)(base + 6291456);     // [2][128][512],   lo at +65536
  bf16*  WoT    = (bf16*)(base + 6553600);     // [2][1024][1024]
  bf16*  W1T    = (bf16*)(base + 10747904);    // [10240][1024]
  bf16*  W3T    = (bf16*)(base + 31719424);    // [10240][1024]
  bf16*  W2T    = (bf16*)(base + 52690944);    // [1024][10240]
  float* hb     = (float*)(base + 73662464);   // [4096][1024] f32
  float* wful   = (float*)(base + 90439680);   // [4096][8]
  char*  AR     = base + 90570752;             // 102,760,448-byte arena
  // attention phase
  bf16* xn  = (bf16*)(AR + 0);          // [2][4096][1024] split   (later: yb)
  bf16* qb  = (bf16*)(AR + 16777216);   // [2][4096][1024] split
  bf16* kb  = (bf16*)(AR + 33554432);   // [2][4096][64]   split
  bf16* vt  = (bf16*)(AR + 34603008);   // [2][4][64][1024] split
  bf16* scp = (bf16*)(AR + 35651584);   // [2][16][1024][1024] split (kvb aliases)
  bf16* kvb = scp;                      // [2][4096][512] split
  bf16* yb  = xn;                       // [2][4096][1024] split
  // moe phase (attention arena dead)
  bf16* hnb = (bf16*)(AR + 0);          // [4096][1024]
  bf16* hid = (bf16*)(AR + 8388608);    // [4096][10240]

  dim3 pblk(32, 8);
  auto packl = [&](const float* src, bf16* dst, int K, int N, int ld, int Z,
                   long srcZ, long dstZ, long plane) {
    dim3 g((N + 31) / 32, (K + 31) / 32, Z);
    hipLaunchKernelGGL(pack_t_kernel, g, pblk, 0, stream, src, dst, K, N, ld, srcZ, dstZ, plane);
  };
  // ---- weight packs ----
  packl(wq, WqT, 1024, 1024, 1024, 1, 0, 0, 1048576);
  packl(wkv_down, WkvT, 1024, 512, 1024, 1, 0, 0, 524288);
  packl(wk_up, WkvupT, 512, 64, 512, 1, 0, 0, 65536);
  packl(wv_up, WkvupT + 64 * 512, 512, 64, 512, 1, 0, 0, 65536);
  packl(wo, WoT, 1024, 1024, 1024, 1, 0, 0, 1048576);
  packl(e_w1, W1T, 1024, 1024, 1024, 8, 1048576, 1048576, 0);
  packl(s_w1, W1T + 8192l * 1024, 1024, 2048, 1024, 1, 0, 0, 0);
  packl(e_w3, W3T, 1024, 1024, 1024, 8, 1048576, 1048576, 0);
  packl(s_w3, W3T + 8192l * 1024, 1024, 2048, 1024, 1, 0, 0, 0);
  packl(e_w2, W2T, 1024, 1024, FUP, 8, 1048576, 1024, 0);
  packl(s_w2, W2T + 8192, 2048, 1024, FUP, 1, 0, 0, 0);

  // ---- attention (split-bf16 chain for routing stability) ----
  hipLaunchKernelGGL((rmsnorm_kernel<true>), dim3(NTOK), dim3(256), 0, stream,
                     x, g_attn, xn, 4194304l);

  hipLaunchKernelGGL((gemm_bt<128, EPI_SPLIT, 1>), dim3(8, 32, 1), dim3(256), 0, stream,
                     xn, 1024l, 4194304l, WqT, WqT + 1048576, 1024l,
                     (void*)qb, 1024l, 4194304l, 4096, 1024, 1024,
                     1, 0l, 0l, 0l, 0l, 0l, 0l, (const float*)nullptr, (void*)nullptr, 0);

  hipLaunchKernelGGL((gemm_bt<128, EPI_SPLIT, 1>), dim3(4, 32, 1), dim3(256), 0, stream,
                     xn, 1024l, 4194304l, WkvT, WkvT + 524288, 1024l,
                     (void*)kvb, 512l, 2097152l, 4096, 512, 1024,
                     1, 0l, 0l, 0l, 0l, 0l, 0l, (const float*)nullptr, (void*)nullptr, 0);

  hipLaunchKernelGGL((gemm_bt<128, EPI_KV, 1>), dim3(1, 32, 1), dim3(256), 0, stream,
                     kvb, 512l, 2097152l, WkvupT, WkvupT + 65536, 512l,
                     (void*)kb, 64l, 0l, 4096, 128, 512,
                     1, 0l, 0l, 0l, 0l, 0l, 0l, (const float*)nullptr, (void*)vt, 0);

  for (int b = 0; b < CB; b++) {
    // QK^T -> split-bf16 scores (causal block-skip)
    hipLaunchKernelGGL((gemm_bt<128, EPI_SPLIT, 1>), dim3(8, 8, 16), dim3(256), 0, stream,
                       qb + (long)b * 1048576, 1024l, 4194304l,
                       kb + (long)b * 65536, kb + (long)b * 65536 + 262144, 64l,
                       (void*)scp, 1024l, 16777216l, 1024, 1024, 64,
                       16, 0l, 64l, 0l, 0l, 0l, 1048576l,
                       (const float*)nullptr, (void*)nullptr, 1);
    // softmax in place (split-bf16 -> split-bf16 P)
    hipLaunchKernelGGL(softmax_kernel, dim3(4096), dim3(256), 0, stream, scp, 16777216l);
    // PV -> yb (split)
    hipLaunchKernelGGL((gemm_bt<64, EPI_SPLIT, 1>), dim3(1, 8, 16), dim3(256), 0, stream,
                       scp, 1024l, 16777216l,
                       vt + (long)b * 65536, vt + (long)b * 65536 + 262144, 1024l,
                       (void*)(yb + (long)b * 1048576), 1024l, 4194304l, 1024, 64, 1024,
                       16, 0l, 1048576l, 0l, 0l, 0l, 64l,
                       (const float*)nullptr, (void*)nullptr, 0);
  }

  // h = x + y@wo
  hipLaunchKernelGGL((gemm_bt<128, EPI_ADD, 1>), dim3(8, 32, 1), dim3(256), 0, stream,
                     yb, 1024l, 4194304l, WoT, WoT + 1048576, 1024l,
                     (void*)hb, 1024l, 0l, 4096, 1024, 1024,
                     1, 0l, 0l, 0l, 0l, 0l, 0l, x, (void*)nullptr, 0);

  // ---- MoE ----
  hipLaunchKernelGGL(router_kernel, dim3(NTOK), dim3(64), 0, stream, hb, g_moe, wr, rb, wful);
  hipLaunchKernelGGL((rmsnorm_kernel<false>), dim3(NTOK), dim3(256), 0, stream,
                     hb, g_moe, hnb, 0l);

  // fused up+gate: hid[n, col] = (x@w1) * silu(x@w3) * wt
  hipLaunchKernelGGL((gemm_bt<64, EPI_SWIGLU, 2>), dim3(FUP / 64, 32, 1), dim3(256), 0, stream,
                     hnb, 1024l, 0l, W1T, W3T, 1024l,
                     (void*)hid, (long)FUP, 0l, 4096, FUP, 1024,
                     1, 0l, 0l, 0l, 0l, 0l, 0l, wful, (void*)nullptr, 0);

  // out = h + hid @ W2all
  hipLaunchKernelGGL((gemm_bt<64, EPI_ADD, 0>), dim3(16, 32, 1), dim3(256), 0, stream,
                     hid, (long)FUP, 0l, W2T, W2T, (long)FUP,
                     (void*)out, 1024l, 0l, 4096, 1024, FUP,
                     1, 0l, 0l, 0l, 0l, 0l, 0l, hb, (void*)nullptr, 0);
}